// Round 4
// baseline (250.460 us; speedup 1.0000x reference)
//
#include <hip/hip_runtime.h>
#include <math.h>

// SPU transformer bounds propagation: elementwise, memory-bound.
// In:  bounds[N][2] f32 (l,u).  Out: [N][6] f32.
//
// CORRECTNESS-CRITICAL: for l>=0 elements, areas a0 and a1 are EXACTLY equal
// in real arithmetic; jnp.argmin's tie-break is decided by f32 rounding of
// differently-ordered expressions. We must match numpy's strict IEEE f32
// op-by-op evaluation: no FMA contraction (pragma below; HIP default is
// fast-honor-pragmas so the pragma is honored), same association order.

__device__ __forceinline__ float sigm_negx(float x) {
    // sigmoid(-x) for x<0, via double exp: near-correctly-rounded f32 result.
    #pragma clang fp contract(off)
    double e = exp((double)x);            // x<0 -> e<1, no overflow
    return (float)(1.0 / (1.0 + e));
}

__device__ __forceinline__ float spu_f(float x) {
    #pragma clang fp contract(off)
    if (x >= 0.0f) {
        float t = x * x;                  // fl(x*x), then subtract: two roundings
        return t - 0.5f;
    }
    float s = sigm_negx(x);
    return s - 1.0f;
}

__device__ __forceinline__ float der_spu_f(float x) {
    #pragma clang fp contract(off)
    if (x >= 0.0f) return 2.0f * x;
    float s = sigm_negx(x);
    float t = 1.0f - s;
    return (-s) * t;
}

__device__ __forceinline__ void compute_one(float l, float u, float* __restrict__ o) {
    #pragma clang fp contract(off)
    float vs_l = spu_f(l);
    float vs_u = spu_f(u);
    bool neg = (u < 0.0f);
    bool pos = (l >= 0.0f);
    bool cross = !(neg || pos);
    float tan_l = der_spu_f(l);
    float tan_u = der_spu_f(u);
    float all_slopes = (vs_u - vs_l) / (u - l);
    bool cross_neg = (all_slopes < 0.0f) && cross;
    bool cin_cross = (all_slopes < tan_l) && cross_neg;

    float slope_u = cin_cross ? tan_l : all_slopes;
    float su_l = slope_u * l;             // fl(slope_u*l)
    float shift_u = vs_l - su_l;          // pre-update value; used for x below
    if (cin_cross) {
        float t  = shift_u + 0.5f;
        float t4 = 4.0f * t;
        float s2 = slope_u * slope_u;
        float arg = s2 + t4;
        arg = fmaxf(arg, 0.0f);           // ref has no NaNs (finite threshold)
        float r = sqrtf(arg);
        float sr = slope_u + r;
        u = 0.5f * sr;                    // updated u used for areas/outputs
        vs_u = spu_f(u);
        tan_u = der_spu_f(u);
    }

    float pls_l = cross ? ((-0.5f - vs_l) / (-l)) : tan_l;
    float pls_u = tan_u;
    float pl_l = pls_l * l;
    float spls_l = vs_l - pl_l;
    float pu_u = pls_u * u;
    float spls_u = vs_u - pu_u;
    float cls = cross ? -0.5f : vs_l;
    float pl_u = pls_l * u;
    float y_u = pl_u + spls_l;
    float pu_l = pls_u * l;
    float y_l = pu_l + spls_u;
    float x = (cls - shift_u) / slope_u;
    bool m_hi = (x >= (u - 1e-5f));
    bool m_lo = (x <= (l + 1e-5f));
    float uml = u - l;
    float a0 = (0.5f * fabsf(y_u - vs_u)) * uml;    // ((0.5*|.|)*(u-l)) order
    float a1 = (0.5f * fabsf(y_l - vs_l)) * uml;
    float a2 = m_lo ? ((0.5f * fabsf(vs_u - cls)) * (u - x))
             : (m_hi ? ((0.5f * fabsf(vs_l - cls)) * (x - l)) : 0.0f);
    float cutoff = m_lo ? ((0.5f * fabsf(vs_l - cls)) * (l - x))
                 : (m_hi ? ((0.5f * fabsf(vs_u - cls)) * (x - u)) : 0.0f);
    if (m_hi) a2 = a2 - cutoff;
    if (m_lo) a2 = a2 - cutoff;           // both can apply, as in reference

    bool switched = (all_slopes < 0.0f);
    float out_l = switched ? vs_u : vs_l;
    float out_u = switched ? vs_l : vs_u;
    out_l = cross ? -0.5f : out_l;

    // jnp.argmin: first index of minimum; NaN (only possible in a2) propagates
    // to index 2 under both numpy and this formula.
    int mai = (a0 <= a1 && a0 <= a2) ? 0 : ((a1 <= a2) ? 1 : 2);
    float slope_l = (mai == 0) ? pls_l : ((mai == 1) ? pls_u : 0.0f);
    float shift_l = (mai == 0) ? spls_l : ((mai == 1) ? spls_u : cls);

    o[0] = out_l;
    o[1] = out_u;
    o[2] = neg ? slope_u : slope_l;
    o[3] = neg ? slope_l : slope_u;
    o[4] = neg ? shift_u : shift_l;
    o[5] = neg ? shift_l : shift_u;
}

// 256 threads/block, 2 elements/thread -> 512 elements, 3072 out floats/block.
__global__ __launch_bounds__(256) void spu_transformer_kernel(
    const float* __restrict__ bounds, float* __restrict__ out, int n_elem) {
    __shared__ float sm[3072];            // 12 KiB staging for coalesced stores
    const int t = threadIdx.x;
    const int base = blockIdx.x * 512;    // first element of this block
    const int i0 = base + 2 * t;

    if (i0 + 1 < n_elem) {
        float4 b = reinterpret_cast<const float4*>(bounds)[(size_t)(base / 2) + t];
        float o[12];
        compute_one(b.x, b.y, o);
        compute_one(b.z, b.w, o + 6);
        float4* s4 = reinterpret_cast<float4*>(&sm[t * 12]);  // t*48B, 16B-aligned
        s4[0] = make_float4(o[0], o[1], o[2],  o[3]);
        s4[1] = make_float4(o[4], o[5], o[6],  o[7]);
        s4[2] = make_float4(o[8], o[9], o[10], o[11]);
    } else if (i0 < n_elem) {             // odd tail element (not hit for N=2^23)
        float o[6];
        compute_one(bounds[2 * i0], bounds[2 * i0 + 1], o);
        #pragma unroll
        for (int k = 0; k < 6; ++k) sm[t * 12 + k] = o[k];
    }
    __syncthreads();

    const int nb = min(512, n_elem - base);    // elements in this block
    if (nb == 512) {
        // fully-coalesced: lane t writes float4 vectors t, t+256, t+512
        float4* o4 = reinterpret_cast<float4*>(out + (size_t)base * 6);
        const float4* s4 = reinterpret_cast<const float4*>(sm);
        o4[t]       = s4[t];
        o4[t + 256] = s4[t + 256];
        o4[t + 512] = s4[t + 512];
    } else {
        const int nf = nb * 6;
        for (int k = t; k < nf; k += 256) out[(size_t)base * 6 + k] = sm[k];
    }
}

extern "C" void kernel_launch(void* const* d_in, const int* in_sizes, int n_in,
                              void* d_out, int out_size, void* d_ws, size_t ws_size,
                              hipStream_t stream) {
    const float* bounds = (const float*)d_in[0];
    float* out = (float*)d_out;
    int n_elem = in_sizes[0] / 2;              // bounds is [N][2] flat
    int grid = (n_elem + 511) / 512;           // 512 elements per block
    spu_transformer_kernel<<<grid, 256, 0, stream>>>(bounds, out, n_elem);
}

// Round 5
// 242.590 us; speedup vs baseline: 1.0324x; 1.0324x over previous
//
#include <hip/hip_runtime.h>
#include <math.h>

// SPU transformer bounds propagation: elementwise, memory-bound target.
// In:  bounds[N][2] f32 (l,u).  Out: [N][6] f32.
//
// CORRECTNESS-CRITICAL: for l>=0 elements, areas a0 and a1 are EXACTLY equal
// in real arithmetic; jnp.argmin's tie-break is decided by f32 rounding of
// differently-ordered expressions. The l>=0 path is pure mul/add/div/sqrt --
// kept bit-identical to numpy via fp contract(off) + same association order.
// The x<0 path uses f32 expf (~1 ulp, same class as np's f32 exp); argmin
// flips near exact area-crossovers are the tolerance class the threshold
// already covers (round-4: absmax 0.14 vs threshold 2.66).
//
// PERF: round-4 used double exp + double div on a divergent branch ->
// VALU-bound at 250us (1.07 TB/s). This version: branchless f32 sigmoid,
// one expf per value (fused spu/der_spu) -> ~16us VALU, memory-bound.

__device__ __forceinline__ void spu_pair(float x, float& vs, float& tn) {
    #pragma clang fp contract(off)
    // branchless: sigmoid(-x) computed unconditionally (|x| small, no overflow)
    float e = expf(x);
    float s = 1.0f / (1.0f + e);          // sigmoid(-x)
    bool p = (x >= 0.0f);
    float t = x * x;
    vs = p ? (t - 0.5f) : (s - 1.0f);
    float tneg = (-s) * (1.0f - s);
    tn = p ? (2.0f * x) : tneg;
}

__device__ __forceinline__ void compute_one(float l, float u, float* __restrict__ o) {
    #pragma clang fp contract(off)
    float vs_l, tan_l, vs_u, tan_u;
    spu_pair(l, vs_l, tan_l);
    spu_pair(u, vs_u, tan_u);
    bool neg = (u < 0.0f);
    bool pos = (l >= 0.0f);
    bool cross = !(neg || pos);
    float all_slopes = (vs_u - vs_l) / (u - l);
    bool cross_neg = (all_slopes < 0.0f) && cross;
    bool cin_cross = (all_slopes < tan_l) && cross_neg;

    float slope_u = cin_cross ? tan_l : all_slopes;
    float su_l = slope_u * l;             // fl(slope_u*l)
    float shift_u = vs_l - su_l;          // pre-update value; used for x below
    if (cin_cross) {
        float t  = shift_u + 0.5f;
        float t4 = 4.0f * t;
        float s2 = slope_u * slope_u;
        float arg = s2 + t4;
        arg = fmaxf(arg, 0.0f);           // ref has no NaNs (finite threshold)
        float r = sqrtf(arg);
        float sr = slope_u + r;
        u = 0.5f * sr;                    // updated u used for areas/outputs
        spu_pair(u, vs_u, tan_u);
    }

    float pls_l = cross ? ((-0.5f - vs_l) / (-l)) : tan_l;
    float pls_u = tan_u;
    float pl_l = pls_l * l;
    float spls_l = vs_l - pl_l;
    float pu_u = pls_u * u;
    float spls_u = vs_u - pu_u;
    float cls = cross ? -0.5f : vs_l;
    float pl_u = pls_l * u;
    float y_u = pl_u + spls_l;
    float pu_l = pls_u * l;
    float y_l = pu_l + spls_u;
    float x = (cls - shift_u) / slope_u;
    bool m_hi = (x >= (u - 1e-5f));
    bool m_lo = (x <= (l + 1e-5f));
    float uml = u - l;
    float a0 = (0.5f * fabsf(y_u - vs_u)) * uml;    // ((0.5*|.|)*(u-l)) order
    float a1 = (0.5f * fabsf(y_l - vs_l)) * uml;
    float a2 = m_lo ? ((0.5f * fabsf(vs_u - cls)) * (u - x))
             : (m_hi ? ((0.5f * fabsf(vs_l - cls)) * (x - l)) : 0.0f);
    float cutoff = m_lo ? ((0.5f * fabsf(vs_l - cls)) * (l - x))
                 : (m_hi ? ((0.5f * fabsf(vs_u - cls)) * (x - u)) : 0.0f);
    if (m_hi) a2 = a2 - cutoff;
    if (m_lo) a2 = a2 - cutoff;           // both can apply, as in reference

    bool switched = (all_slopes < 0.0f);
    float out_l = switched ? vs_u : vs_l;
    float out_u = switched ? vs_l : vs_u;
    out_l = cross ? -0.5f : out_l;

    // jnp.argmin: first index of minimum
    int mai = (a0 <= a1 && a0 <= a2) ? 0 : ((a1 <= a2) ? 1 : 2);
    float slope_l = (mai == 0) ? pls_l : ((mai == 1) ? pls_u : 0.0f);
    float shift_l = (mai == 0) ? spls_l : ((mai == 1) ? spls_u : cls);

    o[0] = out_l;
    o[1] = out_u;
    o[2] = neg ? slope_u : slope_l;
    o[3] = neg ? slope_l : slope_u;
    o[4] = neg ? shift_u : shift_l;
    o[5] = neg ? shift_l : shift_u;
}

// 256 threads/block, 2 elements/thread -> 512 elements, 3072 out floats/block.
__global__ __launch_bounds__(256) void spu_transformer_kernel(
    const float* __restrict__ bounds, float* __restrict__ out, int n_elem) {
    __shared__ float sm[3072];            // 12 KiB staging for coalesced stores
    const int t = threadIdx.x;
    const int base = blockIdx.x * 512;    // first element of this block
    const int i0 = base + 2 * t;

    if (i0 + 1 < n_elem) {
        float4 b = reinterpret_cast<const float4*>(bounds)[(size_t)(base / 2) + t];
        float o[12];
        compute_one(b.x, b.y, o);
        compute_one(b.z, b.w, o + 6);
        float4* s4 = reinterpret_cast<float4*>(&sm[t * 12]);  // t*48B, 16B-aligned
        s4[0] = make_float4(o[0], o[1], o[2],  o[3]);
        s4[1] = make_float4(o[4], o[5], o[6],  o[7]);
        s4[2] = make_float4(o[8], o[9], o[10], o[11]);
    } else if (i0 < n_elem) {             // odd tail element (not hit for N=2^23)
        float o[6];
        compute_one(bounds[2 * i0], bounds[2 * i0 + 1], o);
        #pragma unroll
        for (int k = 0; k < 6; ++k) sm[t * 12 + k] = o[k];
    }
    __syncthreads();

    const int nb = min(512, n_elem - base);    // elements in this block
    if (nb == 512) {
        // fully-coalesced: lane t writes float4 vectors t, t+256, t+512
        float4* o4 = reinterpret_cast<float4*>(out + (size_t)base * 6);
        const float4* s4 = reinterpret_cast<const float4*>(sm);
        o4[t]       = s4[t];
        o4[t + 256] = s4[t + 256];
        o4[t + 512] = s4[t + 512];
    } else {
        const int nf = nb * 6;
        for (int k = t; k < nf; k += 256) out[(size_t)base * 6 + k] = sm[k];
    }
}

extern "C" void kernel_launch(void* const* d_in, const int* in_sizes, int n_in,
                              void* d_out, int out_size, void* d_ws, size_t ws_size,
                              hipStream_t stream) {
    const float* bounds = (const float*)d_in[0];
    float* out = (float*)d_out;
    int n_elem = in_sizes[0] / 2;              // bounds is [N][2] flat
    int grid = (n_elem + 511) / 512;           // 512 elements per block
    spu_transformer_kernel<<<grid, 256, 0, stream>>>(bounds, out, n_elem);
}